// Round 20
// baseline (46.902 us; speedup 1.0000x reference)
//
#include <hip/hip_runtime.h>

#define NB   8192
#define HD   1024
#define HFD  1152
#define NK0  64
#define NK1  256
#define DD   128

typedef __attribute__((ext_vector_type(4))) float  f32x4;
typedef __attribute__((ext_vector_type(8))) __bf16 bf16x8;

__device__ __forceinline__ unsigned short f2bf(float f) {
  unsigned int u = __float_as_uint(f);
  u += 0x7fffu + ((u >> 16) & 1u);
  return (unsigned short)(u >> 16);
}
__device__ __forceinline__ unsigned int pack2(float a, float b) {
  return (unsigned int)f2bf(a) | ((unsigned int)f2bf(b) << 16);
}
__device__ __forceinline__ uint4 pack8(const float4 a, const float4 b) {
  return make_uint4(pack2(a.x, a.y), pack2(a.z, a.w), pack2(b.x, b.y), pack2(b.z, b.w));
}
__device__ __forceinline__ void gload_lds16(const void* g, void* l) {
  __builtin_amdgcn_global_load_lds(
      (const __attribute__((address_space(1))) void*)g,
      (__attribute__((address_space(3))) void*)l, 16, 0, 0);
}

// ---- KG2: R11's kernel VERBATIM (dbuf 2x36.9KB, fully-unrolled K-loop,
// compile-time slot indices => 2-tile prefetch slack on A and B). -----------
__global__ __launch_bounds__(512) void kG2(
    const float* __restrict__ x, const float* __restrict__ Wc,
    const float* __restrict__ Wf, const float* __restrict__ ccb,
    const float* __restrict__ bc, const float* __restrict__ gc,
    const float* __restrict__ betac, const float* __restrict__ bfv,
    const float* __restrict__ gf, const float* __restrict__ betaf,
    const float* __restrict__ fcb,
    float* __restrict__ out0, unsigned short* __restrict__ zf_bf,
    float* __restrict__ zfn, int* __restrict__ ci_g,
    float* __restrict__ coarse_partial, unsigned int* __restrict__ donecnt,
    unsigned short* __restrict__ fcbbf, float* __restrict__ cn_all)
{
  extern __shared__ char smem[];
  const int t = threadIdx.x, bid = blockIdx.x;
  const int lane = t & 63, wid = t >> 6;
  const int l15 = lane & 15, lhi = lane >> 4;
  const int m0 = bid * 32;

  if (bid == 0 && t == 0)
    __hip_atomic_store(donecnt, 0u, __ATOMIC_RELAXED, __HIP_MEMORY_SCOPE_AGENT);

  f32x4 acc[2][2];
#pragma unroll
  for (int m = 0; m < 2; ++m)
#pragma unroll
    for (int n = 0; n < 2; ++n) acc[m][n] = (f32x4){0.f, 0.f, 0.f, 0.f};

  const int axr = t >> 4;
  const int axc = (t & 15) << 2;
  float4 raA[2];
  float4 rbB[2][8];

#define LOADT(kt, s)                                                           \
  {                                                                            \
    raA[s] = *(const float4*)&x[(size_t)(m0 + axr) * HD + (size_t)(kt) * 64 + axc]; \
    _Pragma("unroll")                                                          \
    for (int j = 0; j < 4; ++j) {                                              \
      const int br = (wid << 5) + (j << 3) + (lane >> 3);                      \
      const float* bp = (br < 128 ? Wc + (size_t)br * HD                       \
                                  : Wf + (size_t)(br - 128) * HFD)             \
                        + (size_t)(kt) * 64 + ((lane & 7) << 3);               \
      rbB[s][2 * j]     = *(const float4*)bp;                                  \
      rbB[s][2 * j + 1] = *(const float4*)(bp + 4);                            \
    }                                                                          \
  }
#define WRITET(bufoff, s)                                                      \
  {                                                                            \
    *(uint2*)(smem + (bufoff) + (axr << 7) + ((((t & 15) << 3)) ^ ((axr & 7) << 4))) = \
        make_uint2(pack2(raA[s].x, raA[s].y), pack2(raA[s].z, raA[s].w));      \
    _Pragma("unroll")                                                          \
    for (int j = 0; j < 4; ++j) {                                              \
      const int br = (wid << 5) + (j << 3) + (lane >> 3);                      \
      *(uint4*)(smem + (bufoff) + 4096 + (br << 7) +                           \
                ((((lane & 7) << 4)) ^ ((br & 7) << 4))) =                     \
          pack8(rbB[s][2 * j], rbB[s][2 * j + 1]);                             \
    }                                                                          \
  }

  LOADT(0, 0);
  LOADT(1, 1);
#pragma unroll
  for (int kt = 0; kt < 16; ++kt) {
    const int s = kt & 1;
    const int bo = s * 36864;
    WRITET(bo, s);                       // compiler waits vmcnt for slot regs
    if (kt < 14) LOADT(kt + 2, s);       // refill slot; consumed 2 tiles later
    asm volatile("s_waitcnt lgkmcnt(0)" ::: "memory");
    __builtin_amdgcn_s_barrier();
    __builtin_amdgcn_sched_barrier(0);
    const char* bufA = smem + bo;
    const char* bufB = bufA + 4096;
#pragma unroll
    for (int ks = 0; ks < 2; ++ks) {
      const int kb = (ks << 6) + (lhi << 4);
      const int sa = kb ^ ((l15 & 7) << 4);
      bf16x8 a0 = *(const bf16x8*)(bufA + (l15 << 7) + sa);
      bf16x8 a1 = *(const bf16x8*)(bufA + ((l15 + 16) << 7) + sa);
#pragma unroll
      for (int n = 0; n < 2; ++n) {
        const int rb = (wid << 5) + (n << 4) + l15;
        bf16x8 b = *(const bf16x8*)(bufB + (rb << 7) + (kb ^ ((rb & 7) << 4)));
        acc[0][n] = __builtin_amdgcn_mfma_f32_16x16x32_bf16(a0, b, acc[0][n], 0, 0, 0);
        acc[1][n] = __builtin_amdgcn_mfma_f32_16x16x32_bf16(a1, b, acc[1][n], 0, 0, 0);
      }
    }
    asm volatile("" ::: "memory");
    __builtin_amdgcn_s_barrier();
  }
#undef LOADT
#undef WRITET

  __syncthreads();

  // ---- epilogue LDS overlay (R11 layout, 88448 B) ----
  int*   cxS = (int*)  smem;                              // [32]
  unsigned short* zqb = (unsigned short*)(smem + 128);    // [32][136]
  float* zcf          = (float*)(smem + 9216);            // [32][132]
  float* zff          = (float*)(smem + 26112);           // [32][132]
  unsigned short* cbb = (unsigned short*)(smem + 43008);  // [64][136]
  unsigned short* Wz  = (unsigned short*)(smem + 43008);  // [128][136]
  unsigned short* zbb = (unsigned short*)(smem + 78336);  // [32][136]
  float* zn  = (float*)(smem + 87040);                    // [32]
  float* cnS = (float*)(smem + 87168);                    // [64]
  float* dmS = (float*)(smem + 87424);                    // [4][32]
  int*   imS = (int*)  (smem + 87936);                    // [4][32]

  // E1: distribute acc; stage coarse codebook bf16 + norms
  if (wid < 4) {
#pragma unroll
    for (int m = 0; m < 2; ++m)
#pragma unroll
      for (int n = 0; n < 2; ++n)
#pragma unroll
        for (int r = 0; r < 4; ++r) {
          int row = (m << 4) + (lhi << 2) + r;
          int col = (wid << 5) + (n << 4) + l15;
          zcf[row * 132 + col] = acc[m][n][r] + bc[col];
        }
  } else {
#pragma unroll
    for (int m = 0; m < 2; ++m)
#pragma unroll
      for (int n = 0; n < 2; ++n)
#pragma unroll
        for (int r = 0; r < 4; ++r) {
          int row = (m << 4) + (lhi << 2) + r;
          int col = ((wid - 4) << 5) + (n << 4) + l15;
          zff[row * 132 + col] = acc[m][n][r] + bfv[col];
        }
  }
#pragma unroll
  for (int i = 0; i < 2; ++i) {
    int idx = t + i * 512;
    int row = idx >> 4, p = idx & 15;
    const float4 u0 = *(const float4*)&ccb[(row << 7) + (p << 3)];
    const float4 u1 = *(const float4*)&ccb[(row << 7) + (p << 3) + 4];
    *(uint4*)&cbb[row * 136 + (p << 3)] = pack8(u0, u1);
    float s2 = u0.x*u0.x + u0.y*u0.y + u0.z*u0.z + u0.w*u0.w
             + u1.x*u1.x + u1.y*u1.y + u1.z*u1.z + u1.w*u1.w;
    s2 += __shfl_xor(s2, 1); s2 += __shfl_xor(s2, 2);
    s2 += __shfl_xor(s2, 4); s2 += __shfl_xor(s2, 8);
    if (p == 0) cnS[row] = s2;
  }
  __syncthreads();

  // E2: LN(z_c); ||z||^2; z -> bf16
  {
    const int r = t >> 4, p = t & 15;
    float v[8];
    const float4 u0 = *(const float4*)&zcf[r * 132 + (p << 3)];
    const float4 u1 = *(const float4*)&zcf[r * 132 + (p << 3) + 4];
    v[0]=u0.x; v[1]=u0.y; v[2]=u0.z; v[3]=u0.w; v[4]=u1.x; v[5]=u1.y; v[6]=u1.z; v[7]=u1.w;
    float s = 0.f, s2 = 0.f;
#pragma unroll
    for (int j = 0; j < 8; ++j) { s += v[j]; s2 += v[j] * v[j]; }
#pragma unroll
    for (int off = 1; off < 16; off <<= 1) { s += __shfl_xor(s, off); s2 += __shfl_xor(s2, off); }
    const float mu   = s * (1.f / 128.f);
    const float rstd = rsqrtf(s2 * (1.f / 128.f) - mu * mu + 1e-5f);
    float s2n = 0.f;
#pragma unroll
    for (int j = 0; j < 8; ++j) {
      int col = (p << 3) + j;
      float vv = (v[j] - mu) * rstd * gc[col] + betac[col];
      v[j] = vv; s2n += vv * vv;
    }
#pragma unroll
    for (int off = 1; off < 16; off <<= 1) s2n += __shfl_xor(s2n, off);
    if (p == 0) zn[r] = s2n;
    *(uint4*)&zbb[r * 136 + (p << 3)] =
        make_uint4(pack2(v[0], v[1]), pack2(v[2], v[3]), pack2(v[4], v[5]), pack2(v[6], v[7]));
  }
  __syncthreads();

  // E3: coarse distances via MFMA
  {
    const int cg = wid & 3, zg = wid >> 2;
    f32x4 dacc = (f32x4){0.f, 0.f, 0.f, 0.f};
#pragma unroll
    for (int ks = 0; ks < 4; ++ks) {
      const int lk = (ks << 5) + (lhi << 3);
      bf16x8 a = *(const bf16x8*)&cbb[((cg << 4) + l15) * 136 + lk];
      bf16x8 b = *(const bf16x8*)&zbb[((zg << 4) + l15) * 136 + lk];
      dacc = __builtin_amdgcn_mfma_f32_16x16x32_bf16(a, b, dacc, 0, 0, 0);
    }
    float bd = 3.4e38f; int bi = 0;
#pragma unroll
    for (int r = 0; r < 4; ++r) {
      int code = (cg << 4) + (lhi << 2) + r;
      float d = cnS[code] - 2.f * dacc[r];
      if (d < bd || (d == bd && code < bi)) { bd = d; bi = code; }
    }
#pragma unroll
    for (int off = 16; off < 64; off <<= 1) {
      float od = __shfl_xor(bd, off); int oi = __shfl_xor(bi, off);
      if (od < bd || (od == bd && oi < bi)) { bd = od; bi = oi; }
    }
    if (lhi == 0) { dmS[cg * 32 + (zg << 4) + l15] = bd; imS[cg * 32 + (zg << 4) + l15] = bi; }
  }
  __syncthreads();

  // E4: final coarse argmin + loss partial + ci
  if (t < 32) {
    float bd = dmS[t]; int bi = imS[t];
#pragma unroll
    for (int w = 1; w < 4; ++w) {
      float od = dmS[w * 32 + t]; int oi = imS[w * 32 + t];
      if (od < bd || (od == bd && oi < bi)) { bd = od; bi = oi; }
    }
    ci_g[m0 + t] = bi;
    cxS[t] = bi;
    float lp = bd + zn[t];
#pragma unroll
    for (int off = 1; off < 32; off <<= 1) lp += __shfl_xor(lp, off);
    if (t == 0) coarse_partial[bid] = lp;
  }
  __syncthreads();

  // E5: stage Wfz + zcq(bf16); write out0
  {
#pragma unroll
    for (int i = 0; i < 4; ++i) {
      int idx = t + i * 512;
      int row = idx >> 4, p = idx & 15;
      const float4 w0 = *(const float4*)&Wf[(size_t)row * HFD + 1024 + (p << 3)];
      const float4 w1 = *(const float4*)&Wf[(size_t)row * HFD + 1024 + (p << 3) + 4];
      *(uint4*)&Wz[row * 136 + (p << 3)] = pack8(w0, w1);
    }
    const int r = t >> 4, p = t & 15;
    const int c = cxS[r];
    const float4 q0 = *(const float4*)&ccb[(c << 7) + (p << 3)];
    const float4 q1 = *(const float4*)&ccb[(c << 7) + (p << 3) + 4];
    *(uint4*)&zqb[r * 136 + (p << 3)] = pack8(q0, q1);
    *(float4*)&out0[(size_t)(m0 + r) * DD + (p << 3)]     = q0;
    *(float4*)&out0[(size_t)(m0 + r) * DD + (p << 3) + 4] = q1;
  }
  __syncthreads();

  // E6: zff += zcq @ Wfz^T
  {
    f32x4 a2[2];
    a2[0] = (f32x4){0.f, 0.f, 0.f, 0.f};
    a2[1] = (f32x4){0.f, 0.f, 0.f, 0.f};
#pragma unroll
    for (int ks = 0; ks < 4; ++ks) {
      const int lk = (ks << 5) + (lhi << 3);
      bf16x8 a0 = *(const bf16x8*)&zqb[l15 * 136 + lk];
      bf16x8 a1 = *(const bf16x8*)&zqb[(16 + l15) * 136 + lk];
      bf16x8 b  = *(const bf16x8*)&Wz[((wid << 4) + l15) * 136 + lk];
      a2[0] = __builtin_amdgcn_mfma_f32_16x16x32_bf16(a0, b, a2[0], 0, 0, 0);
      a2[1] = __builtin_amdgcn_mfma_f32_16x16x32_bf16(a1, b, a2[1], 0, 0, 0);
    }
#pragma unroll
    for (int m = 0; m < 2; ++m)
#pragma unroll
      for (int r = 0; r < 4; ++r)
        zff[((m << 4) + (lhi << 2) + r) * 132 + (wid << 4) + l15] += a2[m][r];
  }
  __syncthreads();

  // E7: LN(z_f) -> zf_bf + zfn
  {
    const int r = t >> 4, p = t & 15;
    float v[8];
    const float4 u0 = *(const float4*)&zff[r * 132 + (p << 3)];
    const float4 u1 = *(const float4*)&zff[r * 132 + (p << 3) + 4];
    v[0]=u0.x; v[1]=u0.y; v[2]=u0.z; v[3]=u0.w; v[4]=u1.x; v[5]=u1.y; v[6]=u1.z; v[7]=u1.w;
    float s = 0.f, s2 = 0.f;
#pragma unroll
    for (int j = 0; j < 8; ++j) { s += v[j]; s2 += v[j] * v[j]; }
#pragma unroll
    for (int off = 1; off < 16; off <<= 1) { s += __shfl_xor(s, off); s2 += __shfl_xor(s2, off); }
    const float mu   = s * (1.f / 128.f);
    const float rstd = rsqrtf(s2 * (1.f / 128.f) - mu * mu + 1e-5f);
    float s2n = 0.f;
    unsigned int o[4];
#pragma unroll
    for (int jj = 0; jj < 4; ++jj) {
      int col = (p << 3) + 2 * jj;
      float v0 = (v[2 * jj]     - mu) * rstd * gf[col]     + betaf[col];
      float v1 = (v[2 * jj + 1] - mu) * rstd * gf[col + 1] + betaf[col + 1];
      s2n += v0 * v0 + v1 * v1;
      o[jj] = pack2(v0, v1);
    }
#pragma unroll
    for (int off = 1; off < 16; off <<= 1) s2n += __shfl_xor(s2n, off);
    if (p == 0) zfn[m0 + r] = s2n;
    *(uint4*)&zf_bf[(size_t)(m0 + r) * DD + (p << 3)] = make_uint4(o[0], o[1], o[2], o[3]);
  }

  // E8: convert this block's 64-row slice of fcb -> bf16 + norms
  {
    const int base_row = bid * 64;
#pragma unroll
    for (int i = 0; i < 2; ++i) {
      int idx = t + i * 512;
      int row = idx >> 4, p = idx & 15;
      const float* src = &fcb[((size_t)(base_row + row)) * DD + (p << 3)];
      const float4 u0 = *(const float4*)src;
      const float4 u1 = *(const float4*)(src + 4);
      *(uint4*)&fcbbf[((size_t)(base_row + row)) * DD + (p << 3)] = pack8(u0, u1);
      float s2 = u0.x*u0.x + u0.y*u0.y + u0.z*u0.z + u0.w*u0.w
               + u1.x*u1.x + u1.y*u1.y + u1.z*u1.z + u1.w*u1.w;
      s2 += __shfl_xor(s2, 1); s2 += __shfl_xor(s2, 2);
      s2 += __shfl_xor(s2, 4); s2 += __shfl_xor(s2, 8);
      if (p == 0) cn_all[base_row + row] = s2;
    }
  }
}

// ---- K3F: R19's kernel VERBATIM (XCD-affine, int4 scan, flush-free) -------
__global__ __launch_bounds__(512) void k3f(
    const unsigned short* __restrict__ zf_bf, const unsigned short* __restrict__ fcbbf,
    const float* __restrict__ fcb, const float* __restrict__ cn_all,
    const float* __restrict__ zfn, const int* __restrict__ ci_g,
    float* __restrict__ out1, float* __restrict__ coarse_partial,
    float* __restrict__ fine_partial, float* __restrict__ outL,
    unsigned int* __restrict__ donecnt)
{
  extern __shared__ char smem[];
  char* VbB   = smem;                       // [256][256B] bf16, XOR-swizzled
  char* zfLB  = smem + 65536;               // [16][256B] bf16, XOR-swizzled
  int*   list = (int*)  (smem + 69632);     // [1024]
  int*   ridS = (int*)  (smem + 73728);     // [16]
  float* dmS  = (float*)(smem + 73792);     // [8][16]
  int*   imS  = (int*)  (smem + 74304);     // [8][16]
  int*   fiS  = (int*)  (smem + 74816);     // [16]
  int*   wsum = (int*)  (smem + 74880);     // [16]
  int*   lastF= (int*)  (smem + 74944);     // [1]

  const int bid = blockIdx.x;
  const int g = bid & 63, cx = bid >> 6;    // XCD-affine mapping
  const int t = threadIdx.x, lane = t & 63, wid = t >> 6;
  const int l15 = lane & 15, lhi = lane >> 4;

  // issue async codebook staging FIRST (bf16, source pre-swizzled)
#pragma unroll
  for (int j = 0; j < 8; ++j) {
    const int row = (t >> 4) + j * 32;
    const int c = t & 15;
    const char* src = (const char*)fcbbf +
        ((size_t)(g * NK1 + row) << 8) + ((c ^ (row & 7)) << 4);
    gload_lds16(src, VbB + j * 8192 + t * 16);
  }
  float cnr[2];
#pragma unroll
  for (int n = 0; n < 2; ++n) cnr[n] = cn_all[g * NK1 + wid * 32 + n * 16 + l15];

  // deterministic compaction of {i : ci_g[i]==g}: int4-vectorized scan
  const int seg = t * 16;
  int4 cv[4];
#pragma unroll
  for (int q = 0; q < 4; ++q) cv[q] = *(const int4*)&ci_g[seg + 4 * q];
  int mcount = 0;
#pragma unroll
  for (int q = 0; q < 4; ++q)
    mcount += (cv[q].x == g) + (cv[q].y == g) + (cv[q].z == g) + (cv[q].w == g);
  int v = mcount;
#pragma unroll
  for (int off = 1; off < 64; off <<= 1) {
    int o = __shfl_up(v, off);
    if (lane >= off) v += o;
  }
  if (lane == 63) wsum[wid] = v;
  __syncthreads();
  if (t == 0) {
    int run = 0;
#pragma unroll
    for (int w = 0; w < 8; ++w) { int c = wsum[w]; wsum[w] = run; run += c; }
    wsum[8] = run;
  }
  __syncthreads();
  const int total = wsum[8];
  const int tcap = total > 1024 ? 1024 : total;
  {
    int j = wsum[wid] + v - mcount;
#define PUSH(val, idx) if ((val) == g) { if (j < 1024) list[j] = seg + (idx); ++j; }
#pragma unroll
    for (int q = 0; q < 4; ++q) {
      PUSH(cv[q].x, 4 * q + 0); PUSH(cv[q].y, 4 * q + 1);
      PUSH(cv[q].z, 4 * q + 2); PUSH(cv[q].w, 4 * q + 3);
    }
#undef PUSH
  }
  __syncthreads();

  float lp = 0.f;
  for (int r0 = cx * 16; r0 < tcap; r0 += 128) {
    __syncthreads();
    if (t < 16) ridS[t] = (r0 + t < tcap) ? list[r0 + t] : -1;
    __syncthreads();
    if (wid < 4) {   // gather 16 z_f rows via gload_lds (swizzled source)
      const int row = t >> 4, c = t & 15;
      const int rid = ridS[row];
      const int srow = rid < 0 ? 0 : rid;
      const char* src = (const char*)zf_bf +
          ((size_t)srow << 8) + ((c ^ (row & 7)) << 4);
      gload_lds16(src, zfLB + t * 16);
    }
    __syncthreads();
    f32x4 dacc[2];
    dacc[0] = (f32x4){0.f, 0.f, 0.f, 0.f};
    dacc[1] = (f32x4){0.f, 0.f, 0.f, 0.f};
#pragma unroll
    for (int ks = 0; ks < 4; ++ks) {
      const int kb = (ks << 6) + (lhi << 4);
      bf16x8 a = *(const bf16x8*)(zfLB + (l15 << 8) + (kb ^ ((l15 & 7) << 4)));
#pragma unroll
      for (int n = 0; n < 2; ++n) {
        const int rb = (wid << 5) + (n << 4) + l15;
        bf16x8 b = *(const bf16x8*)(VbB + (rb << 8) + (kb ^ ((rb & 7) << 4)));
        dacc[n] = __builtin_amdgcn_mfma_f32_16x16x32_bf16(b, a, dacc[n], 0, 0, 0);
      }
    }
    {
      float bd = 3.4e38f; int bi = 0;
#pragma unroll
      for (int n = 0; n < 2; ++n)
#pragma unroll
        for (int r = 0; r < 4; ++r) {
          int code = (wid << 5) + (n << 4) + (lhi << 2) + r;
          float d = cnr[n] - 2.f * dacc[n][r];
          if (d < bd || (d == bd && code < bi)) { bd = d; bi = code; }
        }
#pragma unroll
      for (int off = 16; off < 64; off <<= 1) {
        float od = __shfl_xor(bd, off); int oi = __shfl_xor(bi, off);
        if (od < bd || (od == bd && oi < bi)) { bd = od; bi = oi; }
      }
      if (lhi == 0) { dmS[wid * 16 + l15] = bd; imS[wid * 16 + l15] = bi; }
    }
    __syncthreads();
    if (t < 16) {
      float bd = dmS[t]; int bi = imS[t];
#pragma unroll
      for (int w = 1; w < 8; ++w) {
        float od = dmS[w * 16 + t]; int oi = imS[w * 16 + t];
        if (od < bd || (od == bd && oi < bi)) { bd = od; bi = oi; }
      }
      fiS[t] = bi;
      int rid = ridS[t];
      if (rid >= 0) lp += bd + zfn[rid];
    }
    __syncthreads();
    {  // out1 write
      const int row = t >> 5, p = t & 31;
      const int rid = ridS[row];
      if (rid >= 0) {
        const float* qr = &fcb[((size_t)(g * NK1 + fiS[row])) * DD + (p << 2)];
        *(float4*)&out1[(size_t)rid * DD + (p << 2)] = *(const float4*)qr;
      }
    }
  }
#pragma unroll
  for (int off = 1; off < 16; off <<= 1) lp += __shfl_xor(lp, off);

  // flush-free publication (R11): relaxed atomic store -> vmcnt(0) ->
  // relaxed ticket; last block reads partials with relaxed atomic loads.
  __syncthreads();
  if (t == 0) {
    __hip_atomic_store(&fine_partial[g * 8 + cx], lp, __ATOMIC_RELAXED,
                       __HIP_MEMORY_SCOPE_AGENT);
    asm volatile("s_waitcnt vmcnt(0)" ::: "memory");
    unsigned int old = __hip_atomic_fetch_add(donecnt, 1u, __ATOMIC_RELAXED,
                                              __HIP_MEMORY_SCOPE_AGENT);
    lastF[0] = (old == 511u) ? 1 : 0;
  }
  __syncthreads();
  if (lastF[0] && t < 64) {
    float s = 0.f;
#pragma unroll
    for (int i = 0; i < 4; ++i)
      s += __hip_atomic_load(&coarse_partial[t + i * 64], __ATOMIC_RELAXED,
                             __HIP_MEMORY_SCOPE_AGENT);
#pragma unroll
    for (int i = 0; i < 8; ++i)
      s += __hip_atomic_load(&fine_partial[t + i * 64], __ATOMIC_RELAXED,
                             __HIP_MEMORY_SCOPE_AGENT);
#pragma unroll
    for (int off = 1; off < 64; off <<= 1) s += __shfl_xor(s, off);
    if (t == 0) outL[0] = 1.25f * s / 1048576.0f;
  }
}

// ---- launcher: 2 kernel nodes, no memsets ---------------------------------
extern "C" void kernel_launch(void* const* d_in, const int* in_sizes, int n_in,
                              void* d_out, int out_size, void* d_ws, size_t ws_size,
                              hipStream_t stream) {
  const float* x     = (const float*)d_in[0];
  const float* Wc    = (const float*)d_in[1];
  const float* bc    = (const float*)d_in[2];
  const float* gc    = (const float*)d_in[3];
  const float* betac = (const float*)d_in[4];
  const float* ccb   = (const float*)d_in[5];
  const float* Wf    = (const float*)d_in[6];
  const float* bfv   = (const float*)d_in[7];
  const float* gf    = (const float*)d_in[8];
  const float* betaf = (const float*)d_in[9];
  const float* fcb   = (const float*)d_in[10];

  float* out0 = (float*)d_out;
  float* out1 = out0 + (size_t)NB * DD;
  float* outL = out0 + (size_t)2 * NB * DD;

  char* ws = (char*)d_ws;
  unsigned short* zf_bf  = (unsigned short*)(ws);
  float*          zfn    = (float*)(ws + 2097152);
  int*            ci_g   = (int*)(ws + 2129920);
  float* coarse_partial  = (float*)(ws + 2162688);
  float* fine_partial    = (float*)(ws + 2163712);
  unsigned int*   donecnt = (unsigned int*)(ws + 2165760);
  unsigned short* fcbbf  = (unsigned short*)(ws + 2166784);
  float*          cn_all = (float*)(ws + 6361088);

  hipFuncSetAttribute(reinterpret_cast<const void*>(kG2),
                      hipFuncAttributeMaxDynamicSharedMemorySize, 88448);
  hipFuncSetAttribute(reinterpret_cast<const void*>(k3f),
                      hipFuncAttributeMaxDynamicSharedMemorySize, 75264);

  hipLaunchKernelGGL(kG2, dim3(256), dim3(512), 88448, stream,
                     x, Wc, Wf, ccb, bc, gc, betac, bfv, gf, betaf, fcb,
                     out0, zf_bf, zfn, ci_g, coarse_partial, donecnt,
                     fcbbf, cn_all);
  hipLaunchKernelGGL(k3f, dim3(512), dim3(512), 75264, stream,
                     zf_bf, fcbbf, fcb, cn_all, zfn, ci_g, out1,
                     coarse_partial, fine_partial, outL, donecnt);
}

// Round 21
// 46.348 us; speedup vs baseline: 1.0119x; 1.0119x over previous
//
#include <hip/hip_runtime.h>

#define NB   8192
#define HD   1024
#define HFD  1152
#define NK0  64
#define NK1  256
#define DD   128

typedef __attribute__((ext_vector_type(4))) float  f32x4;
typedef __attribute__((ext_vector_type(8))) __bf16 bf16x8;

__device__ __forceinline__ unsigned short f2bf(float f) {
  unsigned int u = __float_as_uint(f);
  u += 0x7fffu + ((u >> 16) & 1u);
  return (unsigned short)(u >> 16);
}
__device__ __forceinline__ unsigned int pack2(float a, float b) {
  return (unsigned int)f2bf(a) | ((unsigned int)f2bf(b) << 16);
}
__device__ __forceinline__ uint4 pack8(const float4 a, const float4 b) {
  return make_uint4(pack2(a.x, a.y), pack2(a.z, a.w), pack2(b.x, b.y), pack2(b.z, b.w));
}
__device__ __forceinline__ void gload_lds16(const void* g, void* l) {
  __builtin_amdgcn_global_load_lds(
      (const __attribute__((address_space(1))) void*)g,
      (__attribute__((address_space(3))) void*)l, 16, 0, 0);
}

// ---- KG2: GEMM(N=256) + LN + coarse VQ + fused zf + fcb convert -----------
// FINAL = R14/R19 (measured best: 46.4 us total). K-loop unrolled x2 with
// NAMED A-slots raA0/raA1 (rule #20), f32 B reg-staged with in-reg convert,
// single LDS buffer, 2 barriers/tile, BM=32, grid 256.
__global__ __launch_bounds__(512) void kG2(
    const float* __restrict__ x, const float* __restrict__ Wc,
    const float* __restrict__ Wf, const float* __restrict__ ccb,
    const float* __restrict__ bc, const float* __restrict__ gc,
    const float* __restrict__ betac, const float* __restrict__ bfv,
    const float* __restrict__ gf, const float* __restrict__ betaf,
    const float* __restrict__ fcb,
    float* __restrict__ out0, unsigned short* __restrict__ zf_bf,
    float* __restrict__ zfn, int* __restrict__ ci_g,
    float* __restrict__ coarse_partial, unsigned int* __restrict__ donecnt,
    unsigned short* __restrict__ fcbbf, float* __restrict__ cn_all)
{
  extern __shared__ char smem[];
  const int t = threadIdx.x, bid = blockIdx.x;
  const int lane = t & 63, wid = t >> 6;
  const int l15 = lane & 15, lhi = lane >> 4;
  const int m0 = bid * 32;

  if (bid == 0 && t == 0)
    __hip_atomic_store(donecnt, 0u, __ATOMIC_RELAXED, __HIP_MEMORY_SCOPE_AGENT);

  f32x4 acc[2][2];
#pragma unroll
  for (int m = 0; m < 2; ++m)
#pragma unroll
    for (int n = 0; n < 2; ++n) acc[m][n] = (f32x4){0.f, 0.f, 0.f, 0.f};

  const int axr = t >> 4;
  const int axc = (t & 15) << 2;
  float4 raA0, raA1;       // named 2-deep x prefetch (static indexing!)
  float4 rbB[8];           // 1-deep B prefetch (constant indices)

#define LOADA(slotvar, kt)                                                     \
  slotvar = *(const float4*)&x[(size_t)(m0 + axr) * HD + (size_t)(kt) * 64 + axc];
#define LOADB(kt)                                                              \
  {                                                                            \
    _Pragma("unroll")                                                          \
    for (int j = 0; j < 4; ++j) {                                              \
      const int br = (wid << 5) + (j << 3) + (lane >> 3);                      \
      const float* bp = (br < 128 ? Wc + (size_t)br * HD                       \
                                  : Wf + (size_t)(br - 128) * HFD)             \
                        + (size_t)(kt) * 64 + ((lane & 7) << 3);               \
      rbB[2 * j]     = *(const float4*)bp;                                     \
      rbB[2 * j + 1] = *(const float4*)(bp + 4);                               \
    }                                                                          \
  }
#define WRITET(slotvar)                                                        \
  {                                                                            \
    *(uint2*)(smem + (axr << 7) + ((((t & 15) << 3)) ^ ((axr & 7) << 4))) =    \
        make_uint2(pack2(slotvar.x, slotvar.y), pack2(slotvar.z, slotvar.w));  \
    _Pragma("unroll")                                                          \
    for (int j = 0; j < 4; ++j) {                                              \
      const int br = (wid << 5) + (j << 3) + (lane >> 3);                      \
      *(uint4*)(smem + 4096 + (br << 7) +                                      \
                ((((lane & 7) << 4)) ^ ((br & 7) << 4))) =                     \
          pack8(rbB[2 * j], rbB[2 * j + 1]);                                   \
    }                                                                          \
  }
#define MFMA_STEP()                                                            \
  {                                                                            \
    asm volatile("s_waitcnt lgkmcnt(0)" ::: "memory");                         \
    __builtin_amdgcn_s_barrier();                                              \
    __builtin_amdgcn_sched_barrier(0);                                         \
    const char* bufA = smem;                                                   \
    const char* bufB = smem + 4096;                                            \
    _Pragma("unroll")                                                          \
    for (int ks = 0; ks < 2; ++ks) {                                           \
      const int kb = (ks << 6) + (lhi << 4);                                   \
      const int sa = kb ^ ((l15 & 7) << 4);                                    \
      bf16x8 a0 = *(const bf16x8*)(bufA + (l15 << 7) + sa);                    \
      bf16x8 a1 = *(const bf16x8*)(bufA + ((l15 + 16) << 7) + sa);             \
      _Pragma("unroll")                                                        \
      for (int n = 0; n < 2; ++n) {                                            \
        const int rb = (wid << 5) + (n << 4) + l15;                            \
        bf16x8 b = *(const bf16x8*)(bufB + (rb << 7) + (kb ^ ((rb & 7) << 4))); \
        acc[0][n] = __builtin_amdgcn_mfma_f32_16x16x32_bf16(a0, b, acc[0][n], 0, 0, 0); \
        acc[1][n] = __builtin_amdgcn_mfma_f32_16x16x32_bf16(a1, b, acc[1][n], 0, 0, 0); \
      }                                                                        \
    }                                                                          \
  }

  LOADA(raA0, 0);
  LOADB(0);
  LOADA(raA1, 1);
#pragma unroll 1
  for (int kt = 0; kt < 16; kt += 2) {
    // even phase: consume raA0 (loaded 2 phases ago)
    if (kt) __builtin_amdgcn_s_barrier();
    WRITET(raA0);
    if (kt + 2 < 16) LOADA(raA0, kt + 2);
    if (kt + 1 < 16) LOADB(kt + 1);
    MFMA_STEP();
    // odd phase: consume raA1
    __builtin_amdgcn_s_barrier();
    WRITET(raA1);
    if (kt + 3 < 16) LOADA(raA1, kt + 3);
    if (kt + 2 < 16) LOADB(kt + 2);
    MFMA_STEP();
  }
#undef LOADA
#undef LOADB
#undef WRITET
#undef MFMA_STEP

  __syncthreads();

  // ---- epilogue LDS overlay (lifetime-packed, 70144 B total) ----
  float* zff          = (float*)smem;                     // [E1-E7] 16896
  float* zcf          = (float*)(smem + 16896);           // [E1-E2] 16896
  unsigned short* zbb = (unsigned short*)(smem + 33792);  // [E2-E3] 8704
  unsigned short* cbb = (unsigned short*)(smem + 42496);  // [E1-E3] 17408
  unsigned short* Wz  = (unsigned short*)(smem + 16896);  // [E5-E6] 34816
  float* zn  = (float*)(smem + 59904);                    // [32]
  float* cnS = (float*)(smem + 60032);                    // [64]
  float* dmS = (float*)(smem + 60288);                    // [4][32]
  int*   imS = (int*)  (smem + 60800);                    // [4][32]
  int*   cxS = (int*)  (smem + 61312);                    // [32]
  unsigned short* zqb = (unsigned short*)(smem + 61440);  // [E5-E6] 8704

  // E1: distribute acc; stage coarse codebook bf16 + norms
  if (wid < 4) {
#pragma unroll
    for (int m = 0; m < 2; ++m)
#pragma unroll
      for (int n = 0; n < 2; ++n)
#pragma unroll
        for (int r = 0; r < 4; ++r) {
          int row = (m << 4) + (lhi << 2) + r;
          int col = (wid << 5) + (n << 4) + l15;
          zcf[row * 132 + col] = acc[m][n][r] + bc[col];
        }
  } else {
#pragma unroll
    for (int m = 0; m < 2; ++m)
#pragma unroll
      for (int n = 0; n < 2; ++n)
#pragma unroll
        for (int r = 0; r < 4; ++r) {
          int row = (m << 4) + (lhi << 2) + r;
          int col = ((wid - 4) << 5) + (n << 4) + l15;
          zff[row * 132 + col] = acc[m][n][r] + bfv[col];
        }
  }
#pragma unroll
  for (int i = 0; i < 2; ++i) {
    int idx = t + i * 512;
    int row = idx >> 4, p = idx & 15;
    const float4 u0 = *(const float4*)&ccb[(row << 7) + (p << 3)];
    const float4 u1 = *(const float4*)&ccb[(row << 7) + (p << 3) + 4];
    *(uint4*)&cbb[row * 136 + (p << 3)] = pack8(u0, u1);
    float s2 = u0.x*u0.x + u0.y*u0.y + u0.z*u0.z + u0.w*u0.w
             + u1.x*u1.x + u1.y*u1.y + u1.z*u1.z + u1.w*u1.w;
    s2 += __shfl_xor(s2, 1); s2 += __shfl_xor(s2, 2);
    s2 += __shfl_xor(s2, 4); s2 += __shfl_xor(s2, 8);
    if (p == 0) cnS[row] = s2;
  }
  __syncthreads();

  // E2: LN(z_c); ||z||^2; z -> bf16
  {
    const int r = t >> 4, p = t & 15;
    float v[8];
    const float4 u0 = *(const float4*)&zcf[r * 132 + (p << 3)];
    const float4 u1 = *(const float4*)&zcf[r * 132 + (p << 3) + 4];
    v[0]=u0.x; v[1]=u0.y; v[2]=u0.z; v[3]=u0.w; v[4]=u1.x; v[5]=u1.y; v[6]=u1.z; v[7]=u1.w;
    float s = 0.f, s2 = 0.f;
#pragma unroll
    for (int j = 0; j < 8; ++j) { s += v[j]; s2 += v[j] * v[j]; }
#pragma unroll
    for (int off = 1; off < 16; off <<= 1) { s += __shfl_xor(s, off); s2 += __shfl_xor(s2, off); }
    const float mu   = s * (1.f / 128.f);
    const float rstd = rsqrtf(s2 * (1.f / 128.f) - mu * mu + 1e-5f);
    float s2n = 0.f;
#pragma unroll
    for (int j = 0; j < 8; ++j) {
      int col = (p << 3) + j;
      float vv = (v[j] - mu) * rstd * gc[col] + betac[col];
      v[j] = vv; s2n += vv * vv;
    }
#pragma unroll
    for (int off = 1; off < 16; off <<= 1) s2n += __shfl_xor(s2n, off);
    if (p == 0) zn[r] = s2n;
    *(uint4*)&zbb[r * 136 + (p << 3)] =
        make_uint4(pack2(v[0], v[1]), pack2(v[2], v[3]), pack2(v[4], v[5]), pack2(v[6], v[7]));
  }
  __syncthreads();

  // E3: coarse distances via MFMA
  {
    const int cg = wid & 3, zg = wid >> 2;
    f32x4 dacc = (f32x4){0.f, 0.f, 0.f, 0.f};
#pragma unroll
    for (int ks = 0; ks < 4; ++ks) {
      const int lk = (ks << 5) + (lhi << 3);
      bf16x8 a = *(const bf16x8*)&cbb[((cg << 4) + l15) * 136 + lk];
      bf16x8 b = *(const bf16x8*)&zbb[((zg << 4) + l15) * 136 + lk];
      dacc = __builtin_amdgcn_mfma_f32_16x16x32_bf16(a, b, dacc, 0, 0, 0);
    }
    float bd = 3.4e38f; int bi = 0;
#pragma unroll
    for (int r = 0; r < 4; ++r) {
      int code = (cg << 4) + (lhi << 2) + r;
      float d = cnS[code] - 2.f * dacc[r];
      if (d < bd || (d == bd && code < bi)) { bd = d; bi = code; }
    }
#pragma unroll
    for (int off = 16; off < 64; off <<= 1) {
      float od = __shfl_xor(bd, off); int oi = __shfl_xor(bi, off);
      if (od < bd || (od == bd && oi < bi)) { bd = od; bi = oi; }
    }
    if (lhi == 0) { dmS[cg * 32 + (zg << 4) + l15] = bd; imS[cg * 32 + (zg << 4) + l15] = bi; }
  }
  __syncthreads();

  // E4: final coarse argmin + loss partial + ci
  if (t < 32) {
    float bd = dmS[t]; int bi = imS[t];
#pragma unroll
    for (int w = 1; w < 4; ++w) {
      float od = dmS[w * 32 + t]; int oi = imS[w * 32 + t];
      if (od < bd || (od == bd && oi < bi)) { bd = od; bi = oi; }
    }
    ci_g[m0 + t] = bi;
    cxS[t] = bi;
    float lp = bd + zn[t];
#pragma unroll
    for (int off = 1; off < 32; off <<= 1) lp += __shfl_xor(lp, off);
    if (t == 0) coarse_partial[bid] = lp;
  }
  __syncthreads();

  // E5: stage Wfz + zcq(bf16); write out0
  {
#pragma unroll
    for (int i = 0; i < 4; ++i) {
      int idx = t + i * 512;
      int row = idx >> 4, p = idx & 15;
      const float4 w0 = *(const float4*)&Wf[(size_t)row * HFD + 1024 + (p << 3)];
      const float4 w1 = *(const float4*)&Wf[(size_t)row * HFD + 1024 + (p << 3) + 4];
      *(uint4*)&Wz[row * 136 + (p << 3)] = pack8(w0, w1);
    }
    const int r = t >> 4, p = t & 15;
    const int c = cxS[r];
    const float4 q0 = *(const float4*)&ccb[(c << 7) + (p << 3)];
    const float4 q1 = *(const float4*)&ccb[(c << 7) + (p << 3) + 4];
    *(uint4*)&zqb[r * 136 + (p << 3)] = pack8(q0, q1);
    *(float4*)&out0[(size_t)(m0 + r) * DD + (p << 3)]     = q0;
    *(float4*)&out0[(size_t)(m0 + r) * DD + (p << 3) + 4] = q1;
  }
  __syncthreads();

  // E6: zff += zcq @ Wfz^T
  {
    f32x4 a2[2];
    a2[0] = (f32x4){0.f, 0.f, 0.f, 0.f};
    a2[1] = (f32x4){0.f, 0.f, 0.f, 0.f};
#pragma unroll
    for (int ks = 0; ks < 4; ++ks) {
      const int lk = (ks << 5) + (lhi << 3);
      bf16x8 a0 = *(const bf16x8*)&zqb[l15 * 136 + lk];
      bf16x8 a1 = *(const bf16x8*)&zqb[(16 + l15) * 136 + lk];
      bf16x8 b  = *(const bf16x8*)&Wz[((wid << 4) + l15) * 136 + lk];
      a2[0] = __builtin_amdgcn_mfma_f32_16x16x32_bf16(a0, b, a2[0], 0, 0, 0);
      a2[1] = __builtin_amdgcn_mfma_f32_16x16x32_bf16(a1, b, a2[1], 0, 0, 0);
    }
#pragma unroll
    for (int m = 0; m < 2; ++m)
#pragma unroll
      for (int r = 0; r < 4; ++r)
        zff[((m << 4) + (lhi << 2) + r) * 132 + (wid << 4) + l15] += a2[m][r];
  }
  __syncthreads();

  // E7: LN(z_f) -> zf_bf + zfn
  {
    const int r = t >> 4, p = t & 15;
    float v[8];
    const float4 u0 = *(const float4*)&zff[r * 132 + (p << 3)];
    const float4 u1 = *(const float4*)&zff[r * 132 + (p << 3) + 4];
    v[0]=u0.x; v[1]=u0.y; v[2]=u0.z; v[3]=u0.w; v[4]=u1.x; v[5]=u1.y; v[6]=u1.z; v[7]=u1.w;
    float s = 0.f, s2 = 0.f;
#pragma unroll
    for (int j = 0; j < 8; ++j) { s += v[j]; s2 += v[j] * v[j]; }
#pragma unroll
    for (int off = 1; off < 16; off <<= 1) { s += __shfl_xor(s, off); s2 += __shfl_xor(s2, off); }
    const float mu   = s * (1.f / 128.f);
    const float rstd = rsqrtf(s2 * (1.f / 128.f) - mu * mu + 1e-5f);
    float s2n = 0.f;
    unsigned int o[4];
#pragma unroll
    for (int jj = 0; jj < 4; ++jj) {
      int col = (p << 3) + 2 * jj;
      float v0 = (v[2 * jj]     - mu) * rstd * gf[col]     + betaf[col];
      float v1 = (v[2 * jj + 1] - mu) * rstd * gf[col + 1] + betaf[col + 1];
      s2n += v0 * v0 + v1 * v1;
      o[jj] = pack2(v0, v1);
    }
#pragma unroll
    for (int off = 1; off < 16; off <<= 1) s2n += __shfl_xor(s2n, off);
    if (p == 0) zfn[m0 + r] = s2n;
    *(uint4*)&zf_bf[(size_t)(m0 + r) * DD + (p << 3)] = make_uint4(o[0], o[1], o[2], o[3]);
  }

  // E8: convert this block's 64-row slice of fcb -> bf16 + norms
  {
    const int base_row = bid * 64;
#pragma unroll
    for (int i = 0; i < 2; ++i) {
      int idx = t + i * 512;
      int row = idx >> 4, p = idx & 15;
      const float* src = &fcb[((size_t)(base_row + row)) * DD + (p << 3)];
      const float4 u0 = *(const float4*)src;
      const float4 u1 = *(const float4*)(src + 4);
      *(uint4*)&fcbbf[((size_t)(base_row + row)) * DD + (p << 3)] = pack8(u0, u1);
      float s2 = u0.x*u0.x + u0.y*u0.y + u0.z*u0.z + u0.w*u0.w
               + u1.x*u1.x + u1.y*u1.y + u1.z*u1.z + u1.w*u1.w;
      s2 += __shfl_xor(s2, 1); s2 += __shfl_xor(s2, 2);
      s2 += __shfl_xor(s2, 4); s2 += __shfl_xor(s2, 8);
      if (p == 0) cn_all[base_row + row] = s2;
    }
  }
}

// ---- K3F: fine VQ. 1-D grid, XCD-affine group mapping ---------------------
__global__ __launch_bounds__(512) void k3f(
    const unsigned short* __restrict__ zf_bf, const unsigned short* __restrict__ fcbbf,
    const float* __restrict__ fcb, const float* __restrict__ cn_all,
    const float* __restrict__ zfn, const int* __restrict__ ci_g,
    float* __restrict__ out1, float* __restrict__ coarse_partial,
    float* __restrict__ fine_partial, float* __restrict__ outL,
    unsigned int* __restrict__ donecnt)
{
  extern __shared__ char smem[];
  char* VbB   = smem;                       // [256][256B] bf16, XOR-swizzled
  char* zfLB  = smem + 65536;               // [16][256B] bf16, XOR-swizzled
  int*   list = (int*)  (smem + 69632);     // [1024]
  int*   ridS = (int*)  (smem + 73728);     // [16]
  float* dmS  = (float*)(smem + 73792);     // [8][16]
  int*   imS  = (int*)  (smem + 74304);     // [8][16]
  int*   fiS  = (int*)  (smem + 74816);     // [16]
  int*   wsum = (int*)  (smem + 74880);     // [16]
  int*   lastF= (int*)  (smem + 74944);     // [1]

  const int bid = blockIdx.x;
  const int g = bid & 63, cx = bid >> 6;    // XCD-affine mapping
  const int t = threadIdx.x, lane = t & 63, wid = t >> 6;
  const int l15 = lane & 15, lhi = lane >> 4;

  // issue async codebook staging FIRST (bf16, source pre-swizzled)
#pragma unroll
  for (int j = 0; j < 8; ++j) {
    const int row = (t >> 4) + j * 32;
    const int c = t & 15;
    const char* src = (const char*)fcbbf +
        ((size_t)(g * NK1 + row) << 8) + ((c ^ (row & 7)) << 4);
    gload_lds16(src, VbB + j * 8192 + t * 16);
  }
  float cnr[2];
#pragma unroll
  for (int n = 0; n < 2; ++n) cnr[n] = cn_all[g * NK1 + wid * 32 + n * 16 + l15];

  // deterministic compaction of {i : ci_g[i]==g}: int4-vectorized scan
  const int seg = t * 16;
  int4 cv[4];
#pragma unroll
  for (int q = 0; q < 4; ++q) cv[q] = *(const int4*)&ci_g[seg + 4 * q];
  int mcount = 0;
#pragma unroll
  for (int q = 0; q < 4; ++q)
    mcount += (cv[q].x == g) + (cv[q].y == g) + (cv[q].z == g) + (cv[q].w == g);
  int v = mcount;
#pragma unroll
  for (int off = 1; off < 64; off <<= 1) {
    int o = __shfl_up(v, off);
    if (lane >= off) v += o;
  }
  if (lane == 63) wsum[wid] = v;
  __syncthreads();
  if (t == 0) {
    int run = 0;
#pragma unroll
    for (int w = 0; w < 8; ++w) { int c = wsum[w]; wsum[w] = run; run += c; }
    wsum[8] = run;
  }
  __syncthreads();
  const int total = wsum[8];
  const int tcap = total > 1024 ? 1024 : total;
  {
    int j = wsum[wid] + v - mcount;
#define PUSH(val, idx) if ((val) == g) { if (j < 1024) list[j] = seg + (idx); ++j; }
#pragma unroll
    for (int q = 0; q < 4; ++q) {
      PUSH(cv[q].x, 4 * q + 0); PUSH(cv[q].y, 4 * q + 1);
      PUSH(cv[q].z, 4 * q + 2); PUSH(cv[q].w, 4 * q + 3);
    }
#undef PUSH
  }
  __syncthreads();

  float lp = 0.f;
  for (int r0 = cx * 16; r0 < tcap; r0 += 128) {
    __syncthreads();
    if (t < 16) ridS[t] = (r0 + t < tcap) ? list[r0 + t] : -1;
    __syncthreads();
    if (wid < 4) {   // gather 16 z_f rows via gload_lds (swizzled source)
      const int row = t >> 4, c = t & 15;
      const int rid = ridS[row];
      const int srow = rid < 0 ? 0 : rid;
      const char* src = (const char*)zf_bf +
          ((size_t)srow << 8) + ((c ^ (row & 7)) << 4);
      gload_lds16(src, zfLB + t * 16);
    }
    __syncthreads();
    f32x4 dacc[2];
    dacc[0] = (f32x4){0.f, 0.f, 0.f, 0.f};
    dacc[1] = (f32x4){0.f, 0.f, 0.f, 0.f};
#pragma unroll
    for (int ks = 0; ks < 4; ++ks) {
      const int kb = (ks << 6) + (lhi << 4);
      bf16x8 a = *(const bf16x8*)(zfLB + (l15 << 8) + (kb ^ ((l15 & 7) << 4)));
#pragma unroll
      for (int n = 0; n < 2; ++n) {
        const int rb = (wid << 5) + (n << 4) + l15;
        bf16x8 b = *(const bf16x8*)(VbB + (rb << 8) + (kb ^ ((rb & 7) << 4)));
        dacc[n] = __builtin_amdgcn_mfma_f32_16x16x32_bf16(b, a, dacc[n], 0, 0, 0);
      }
    }
    {
      float bd = 3.4e38f; int bi = 0;
#pragma unroll
      for (int n = 0; n < 2; ++n)
#pragma unroll
        for (int r = 0; r < 4; ++r) {
          int code = (wid << 5) + (n << 4) + (lhi << 2) + r;
          float d = cnr[n] - 2.f * dacc[n][r];
          if (d < bd || (d == bd && code < bi)) { bd = d; bi = code; }
        }
#pragma unroll
      for (int off = 16; off < 64; off <<= 1) {
        float od = __shfl_xor(bd, off); int oi = __shfl_xor(bi, off);
        if (od < bd || (od == bd && oi < bi)) { bd = od; bi = oi; }
      }
      if (lhi == 0) { dmS[wid * 16 + l15] = bd; imS[wid * 16 + l15] = bi; }
    }
    __syncthreads();
    if (t < 16) {
      float bd = dmS[t]; int bi = imS[t];
#pragma unroll
      for (int w = 1; w < 8; ++w) {
        float od = dmS[w * 16 + t]; int oi = imS[w * 16 + t];
        if (od < bd || (od == bd && oi < bi)) { bd = od; bi = oi; }
      }
      fiS[t] = bi;
      int rid = ridS[t];
      if (rid >= 0) lp += bd + zfn[rid];
    }
    __syncthreads();
    {  // out1 write
      const int row = t >> 5, p = t & 31;
      const int rid = ridS[row];
      if (rid >= 0) {
        const float* qr = &fcb[((size_t)(g * NK1 + fiS[row])) * DD + (p << 2)];
        *(float4*)&out1[(size_t)rid * DD + (p << 2)] = *(const float4*)qr;
      }
    }
  }
#pragma unroll
  for (int off = 1; off < 16; off <<= 1) lp += __shfl_xor(lp, off);

  // flush-free publication (R11): relaxed atomic store -> vmcnt(0) ->
  // relaxed ticket; last block reads partials with relaxed atomic loads.
  __syncthreads();
  if (t == 0) {
    __hip_atomic_store(&fine_partial[g * 8 + cx], lp, __ATOMIC_RELAXED,
                       __HIP_MEMORY_SCOPE_AGENT);
    asm volatile("s_waitcnt vmcnt(0)" ::: "memory");
    unsigned int old = __hip_atomic_fetch_add(donecnt, 1u, __ATOMIC_RELAXED,
                                              __HIP_MEMORY_SCOPE_AGENT);
    lastF[0] = (old == 511u) ? 1 : 0;
  }
  __syncthreads();
  if (lastF[0] && t < 64) {
    float s = 0.f;
#pragma unroll
    for (int i = 0; i < 4; ++i)
      s += __hip_atomic_load(&coarse_partial[t + i * 64], __ATOMIC_RELAXED,
                             __HIP_MEMORY_SCOPE_AGENT);
#pragma unroll
    for (int i = 0; i < 8; ++i)
      s += __hip_atomic_load(&fine_partial[t + i * 64], __ATOMIC_RELAXED,
                             __HIP_MEMORY_SCOPE_AGENT);
#pragma unroll
    for (int off = 1; off < 64; off <<= 1) s += __shfl_xor(s, off);
    if (t == 0) outL[0] = 1.25f * s / 1048576.0f;
  }
}

// ---- launcher: 2 kernel nodes, no memsets ---------------------------------
extern "C" void kernel_launch(void* const* d_in, const int* in_sizes, int n_in,
                              void* d_out, int out_size, void* d_ws, size_t ws_size,
                              hipStream_t stream) {
  const float* x     = (const float*)d_in[0];
  const float* Wc    = (const float*)d_in[1];
  const float* bc    = (const float*)d_in[2];
  const float* gc    = (const float*)d_in[3];
  const float* betac = (const float*)d_in[4];
  const float* ccb   = (const float*)d_in[5];
  const float* Wf    = (const float*)d_in[6];
  const float* bfv   = (const float*)d_in[7];
  const float* gf    = (const float*)d_in[8];
  const float* betaf = (const float*)d_in[9];
  const float* fcb   = (const float*)d_in[10];

  float* out0 = (float*)d_out;
  float* out1 = out0 + (size_t)NB * DD;
  float* outL = out0 + (size_t)2 * NB * DD;

  char* ws = (char*)d_ws;
  unsigned short* zf_bf  = (unsigned short*)(ws);
  float*          zfn    = (float*)(ws + 2097152);
  int*            ci_g   = (int*)(ws + 2129920);
  float* coarse_partial  = (float*)(ws + 2162688);
  float* fine_partial    = (float*)(ws + 2163712);
  unsigned int*   donecnt = (unsigned int*)(ws + 2165760);
  unsigned short* fcbbf  = (unsigned short*)(ws + 2166784);
  float*          cn_all = (float*)(ws + 6361088);

  hipFuncSetAttribute(reinterpret_cast<const void*>(kG2),
                      hipFuncAttributeMaxDynamicSharedMemorySize, 70144);
  hipFuncSetAttribute(reinterpret_cast<const void*>(k3f),
                      hipFuncAttributeMaxDynamicSharedMemorySize, 75264);

  hipLaunchKernelGGL(kG2, dim3(256), dim3(512), 70144, stream,
                     x, Wc, Wf, ccb, bc, gc, betac, bfv, gf, betaf, fcb,
                     out0, zf_bf, zfn, ci_g, coarse_partial, donecnt,
                     fcbbf, cn_all);
  hipLaunchKernelGGL(k3f, dim3(512), dim3(512), 75264, stream,
                     zf_bf, fcbbf, fcb, cn_all, zfn, ci_g, out1,
                     coarse_partial, fine_partial, outL, donecnt);
}